// Round 11
// baseline (109.980 us; speedup 1.0000x reference)
//
#include <hip/hip_runtime.h>
#include <hip/hip_bf16.h>

#define EPSV 1e-5f

typedef __attribute__((ext_vector_type(8))) short short8v;
typedef __attribute__((ext_vector_type(4))) short short4v;
typedef __attribute__((ext_vector_type(4))) float float4v;

__device__ inline unsigned short f2bf(float x) {
  __hip_bfloat16 h = __float2bfloat16(x);   // RNE
  return *reinterpret_cast<unsigned short*>(&h);
}
__device__ inline float bf2f(unsigned short b) {
  unsigned u = ((unsigned)b) << 16;
  float f;
  __builtin_memcpy(&f, &u, 4);
  return f;
}

// raw barrier (no implicit waitcnt drain); "memory" pins compiler ordering
__device__ __forceinline__ void bar_raw() {
  asm volatile("s_barrier" ::: "memory");
}
// LDS-only barrier for the legacy (reg-staged) paths
__device__ __forceinline__ void bar_lds() {
  asm volatile("s_waitcnt lgkmcnt(0)\n\ts_barrier" ::: "memory");
}
template <int N>
__device__ __forceinline__ void wait_vmcnt() {
  if constexpr (N == 0) asm volatile("s_waitcnt vmcnt(0)" ::: "memory");
  else if constexpr (N == 3) asm volatile("s_waitcnt vmcnt(3)" ::: "memory");
  else if constexpr (N == 5) asm volatile("s_waitcnt vmcnt(5)" ::: "memory");
}

// direct global->LDS, 16B per lane; lds dest = uniform base + lane*16
__device__ __forceinline__ void gload_lds16(const float* g, float* l) {
  __builtin_amdgcn_global_load_lds(
      (const __attribute__((address_space(1))) void*)(unsigned long long)(uintptr_t)g,
      (__attribute__((address_space(3))) void*)l, 16, 0, 0);
}

// issue one row's chunks owned by this wave (CPW uniform; tail chunk masked;
// waves past NC re-issue the tail chunk idempotently to keep vmcnt uniform)
template <int NC, int CPW, int TAIL_LANES>
__device__ __forceinline__ void issue_row(
    const float* __restrict__ rowp, float* __restrict__ buf, int wv, int lane) {
  #pragma unroll
  for (int j = 0; j < CPW; ++j) {
    int c = wv * CPW + j;
    if (c > NC - 1) c = NC - 1;
    const float* g = rowp + c * 256 + lane * 4;
    float* l = buf + c * 256;
    if (c == NC - 1) {
      if (lane < TAIL_LANES) gload_lds16(g, l);
    } else {
      gload_lds16(g, l);
    }
  }
}

// ---- pool stages 1/2: double-buffered direct-to-LDS pipeline ---------------
// L floats/row, NC = ceil(L*4/1024) chunks, CPW chunks per wave.
template <int L, int MAXW, int ROWS, int CH, int CHOFF, int NC, int CPW, int TAIL_LANES>
__device__ __forceinline__ void pool_rows_dma(
    const float* __restrict__ srcBase, int row0, float wst,
    unsigned short* __restrict__ fusedb, float* __restrict__ buf0,
    float* __restrict__ buf1, int t) {
  int wv = t >> 6, lane = t & 63;
  issue_row<NC, CPW, TAIL_LANES>(srcBase + (size_t)row0 * L, buf0, wv, lane);
  issue_row<NC, CPW, TAIL_LANES>(srcBase + (size_t)(row0 + 1) * L, buf1, wv, lane);
  if (t < MAXW) { buf0[L + t] = 0.f; buf1[L + t] = 0.f; }   // zero pads once
  asm volatile("s_waitcnt lgkmcnt(0)" ::: "memory");
  #pragma unroll
  for (int r = 0; r < ROWS; ++r) {
    float* cur = (r & 1) ? buf1 : buf0;
    if (r < ROWS - 1) wait_vmcnt<CPW>();   // row r landed; row r+1 stays in flight
    else wait_vmcnt<0>();
    bar_raw();
    int start = (t * L) >> 8;
    int end = ((t + 1) * L + 255) >> 8;
    int width = end - start;
    float s = 0.f;
    #pragma unroll
    for (int i = 0; i < MAXW; ++i) {
      float v = cur[start + i];
      s += (i < width) ? v : 0.f;
    }
    int rr = row0 + r;
    int b = rr / CH, c = rr % CH;
    fusedb[((size_t)b * 448 + CHOFF + c) * 256 + t] = f2bf(s / (float)width * wst);
    bar_raw();                              // all waves done reading cur
    if (r + 2 < ROWS)
      issue_row<NC, CPW, TAIL_LANES>(srcBase + (size_t)(row0 + r + 2) * L, cur, wv, lane);
  }
}

// ---- stage3: scalar reg-staged multi-row (R9-proven) -----------------------
template <int L, int MAXW, int ROWS, int CH, int CHOFF>
__device__ __forceinline__ void pool_rows_scalar(
    const float* __restrict__ srcBase, int row0, float wst,
    unsigned short* __restrict__ fusedb, float* __restrict__ row, int t) {
  constexpr int NLD = (L + 255) / 256;
  float buf[NLD];
  {
    const float* rp = srcBase + (size_t)row0 * L;
    #pragma unroll
    for (int i = 0; i < NLD; ++i) {
      int idx = t + 256 * i;
      if (idx < L) buf[i] = __builtin_nontemporal_load(rp + idx);
    }
  }
  if (t < MAXW) row[L + t] = 0.f;
  #pragma unroll 1
  for (int r = 0; r < ROWS; ++r) {
    #pragma unroll
    for (int i = 0; i < NLD; ++i) {
      int idx = t + 256 * i;
      if (idx < L) row[idx] = buf[i];
    }
    bar_lds();
    if (r + 1 < ROWS) {
      const float* rpn = srcBase + (size_t)(row0 + r + 1) * L;
      #pragma unroll
      for (int i = 0; i < NLD; ++i) {
        int idx = t + 256 * i;
        if (idx < L) buf[i] = __builtin_nontemporal_load(rpn + idx);
      }
    }
    int start = (t * L) >> 8;
    int end = ((t + 1) * L + 255) >> 8;
    int width = end - start;
    float s = 0.f;
    #pragma unroll
    for (int i = 0; i < MAXW; ++i) {
      float v = row[start + i];
      s += (i < width) ? v : 0.f;
    }
    int rr = row0 + r;
    int b = rr / CH, c = rr % CH;
    fusedb[((size_t)b * 448 + CHOFF + c) * 256 + t] = f2bf(s / (float)width * wst);
    bar_lds();
  }
}

// ------------- Kernel 1: pool (+softmax scale) with quant tail blocks -------
// s1: [0,2048) x8 rows   s2: [2048,3072) x8 rows   s3: [3072,3328) x16 rows
// quant: [3328,3456)
__global__ __launch_bounds__(256) void pool_quant_kernel(
    const float* __restrict__ s1, const float* __restrict__ s2,
    const float* __restrict__ s3, const float* __restrict__ alpha,
    const float* __restrict__ w, unsigned short* __restrict__ fusedb,
    unsigned short* __restrict__ qbf, float* __restrict__ scales) {
  __shared__ float pool_lds[2][5024];     // 40,192 B -> 4 blocks/CU
  int bid = blockIdx.x;
  int t = threadIdx.x;

  if (bid >= 3328) {                // ---- quant tail ----
    int o = bid - 3328;             // 0..127
    const float* wr = w + o * 448;
    float m = 0.f;
    for (int c = t; c < 448; c += 256) m = fmaxf(m, fabsf(wr[c]));
    float* sm = pool_lds[0];        // reuse LDS
    for (int off = 32; off; off >>= 1) m = fmaxf(m, __shfl_down(m, off, 64));
    if ((t & 63) == 0) sm[t >> 6] = m;
    __syncthreads();
    m = fmaxf(fmaxf(sm[0], sm[1]), fmaxf(sm[2], sm[3]));
    float scale = fmaxf(m, 1e-8f);  // qp = 1 for 2-bit symmetric
    for (int c = t; c < 448; c += 256) {
      float q = rintf(wr[c] / scale);      // RNE == jnp.round
      q = fminf(fmaxf(q, -2.f), 1.f);
      qbf[o * 448 + c] = f2bf(q);          // q in {-2,-1,0,1}: exact bf16
    }
    if (t == 0) scales[o] = scale;
    return;
  }

  float a0 = alpha[0], a1 = alpha[1], a2 = alpha[2];
  float mx = fmaxf(a0, fmaxf(a1, a2));
  float e0 = expf(a0 - mx), e1 = expf(a1 - mx), e2 = expf(a2 - mx);
  float esum = e0 + e1 + e2;

  if (bid < 2048) {                 // ---- stage1: L=5000, NC=20, CPW=5 ----
    pool_rows_dma<5000, 21, 8, 256, 0, 20, 5, 34>(
        s1, bid * 8, e0 / esum, fusedb, pool_lds[0], pool_lds[1], t);
  } else if (bid < 3072) {          // ---- stage2: L=2500, NC=10, CPW=3 ----
    pool_rows_dma<2500, 11, 8, 128, 256, 10, 3, 49>(
        s2, (bid - 2048) * 8, e1 / esum, fusedb, pool_lds[0], pool_lds[1], t);
  } else {                          // ---- stage3: L=625, 16 rows/block ----
    pool_rows_scalar<625, 4, 16, 64, 384>(
        s3, (bid - 3072) * 16, e2 / esum, fusedb, pool_lds[0], t);
  }
}

// ------------- Kernel 2: MFMA GEMM -> bf16 y + BN partials ------------------
__global__ __launch_bounds__(256) void mfma_gemm_kernel(
    const unsigned short* __restrict__ qbf, const float* __restrict__ scales,
    const unsigned short* __restrict__ fusedb, const float* __restrict__ bias,
    unsigned short* __restrict__ ybf, float* __restrict__ Psum,
    float* __restrict__ Pssq) {
  __shared__ __align__(16) unsigned short Asm[64][40];
  __shared__ __align__(16) unsigned Bsm32[16][66];   // [k-pair 0..15][n 0..63]
  int b = blockIdx.z;
  int o0 = blockIdx.y * 64;
  int l0 = blockIdx.x * 64;
  int tid = threadIdx.x;
  int wave = tid >> 6, lane = tid & 63;
  int wm = wave >> 1, wn = wave & 1;
  int lrow = lane & 15, lg = lane >> 4;
  const unsigned short* Fp = fusedb + (size_t)b * 448 * 256;
  float4v acc[2][2];
  #pragma unroll
  for (int i = 0; i < 2; ++i)
    #pragma unroll
    for (int j = 0; j < 2; ++j) acc[i][j] = (float4v){0.f, 0.f, 0.f, 0.f};
  for (int c0 = 0; c0 < 448; c0 += 32) {
    { int r = tid >> 2, k0 = (tid & 3) * 8;
      *(short8v*)&Asm[r][k0] = *(const short8v*)(qbf + (size_t)(o0 + r) * 448 + c0 + k0); }
    { int kp = tid >> 4, n0 = (tid & 15) * 4;
      const unsigned short* g0 = Fp + (size_t)(c0 + 2 * kp) * 256 + l0 + n0;
      short4v v0 = *(const short4v*)g0;
      short4v v1 = *(const short4v*)(g0 + 256);
      #pragma unroll
      for (int j = 0; j < 4; ++j)
        Bsm32[kp][n0 + j] =
            (((unsigned)(unsigned short)v1[j]) << 16) | (unsigned short)v0[j];
    }
    __syncthreads();
    short8v af[2];
    #pragma unroll
    for (int mf = 0; mf < 2; ++mf)
      af[mf] = *(const short8v*)&Asm[wm * 32 + mf * 16 + lrow][lg * 8];
    #pragma unroll
    for (int nf = 0; nf < 2; ++nf) {
      int n = wn * 32 + nf * 16 + lrow;
      int tmp[4];
      #pragma unroll
      for (int jj = 0; jj < 4; ++jj) tmp[jj] = (int)Bsm32[lg * 4 + jj][n];
      short8v bf;
      __builtin_memcpy(&bf, tmp, 16);
      #pragma unroll
      for (int mf = 0; mf < 2; ++mf)
        acc[mf][nf] = __builtin_amdgcn_mfma_f32_16x16x32_bf16(af[mf], bf, acc[mf][nf], 0, 0, 0);
    }
    __syncthreads();
  }
  float sv[2][4], qv[2][4];
  #pragma unroll
  for (int mf = 0; mf < 2; ++mf) {
    #pragma unroll
    for (int reg = 0; reg < 4; ++reg) {
      int r = o0 + wm * 32 + mf * 16 + lg * 4 + reg;
      float sc = scales[r], bv = bias[r];
      float s = 0.f, q = 0.f;
      #pragma unroll
      for (int nf = 0; nf < 2; ++nf) {
        int col = l0 + wn * 32 + nf * 16 + lrow;
        float val = acc[mf][nf][reg] * sc + bv;
        ybf[((size_t)b * 128 + r) * 256 + col] = f2bf(val);
        s += val; q += val * val;              // partials from f32 (pre-round)
      }
      sv[mf][reg] = s; qv[mf][reg] = q;
    }
  }
  #pragma unroll
  for (int mf = 0; mf < 2; ++mf)
    #pragma unroll
    for (int reg = 0; reg < 4; ++reg)
      #pragma unroll
      for (int m = 1; m < 16; m <<= 1) {
        sv[mf][reg] += __shfl_xor(sv[mf][reg], m, 64);
        qv[mf][reg] += __shfl_xor(qv[mf][reg], m, 64);
      }
  if (lrow == 0) {
    int slot = b * 8 + blockIdx.x * 2 + wn;   // 0..511 fixed slot
    #pragma unroll
    for (int mf = 0; mf < 2; ++mf)
      #pragma unroll
      for (int reg = 0; reg < 4; ++reg) {
        int r = o0 + wm * 32 + mf * 16 + lg * 4 + reg;
        Psum[r * 512 + slot] = sv[mf][reg];
        Pssq[r * 512 + slot] = qv[mf][reg];
      }
  }
}

// ------------- Kernel 3: inline stats + BN + ELU + mean over L --------------
__global__ __launch_bounds__(256) void final_kernel(
    const unsigned short* __restrict__ ybf, const float* __restrict__ Psum,
    const float* __restrict__ Pssq, const float* __restrict__ gamma,
    const float* __restrict__ beta, float* __restrict__ out) {
  int w = threadIdx.x >> 6;
  int lane = threadIdx.x & 63;
  int bo = blockIdx.x * 4 + w;     // b*128 + o
  int o = bo & 127;

  float s = 0.f, q = 0.f;
  const float* Pp = Psum + o * 512 + lane * 8;
  const float* Qp = Pssq + o * 512 + lane * 8;
  #pragma unroll
  for (int i = 0; i < 8; ++i) { s += Pp[i]; q += Qp[i]; }
  #pragma unroll
  for (int m = 1; m < 64; m <<= 1) {
    s += __shfl_xor(s, m, 64);
    q += __shfl_xor(q, m, 64);
  }
  float mean = s * (1.f / 16384.f);
  float var = q * (1.f / 16384.f) - mean * mean;
  float rs = rsqrtf(var + EPSV);
  float a = rs * gamma[o];
  float bb = beta[o] - mean * a;

  ushort4 v = *(const ushort4*)(ybf + (size_t)bo * 256 + lane * 4);
  float acc = 0.f;
  #pragma unroll
  for (int j = 0; j < 4; ++j) {
    float e = bf2f((&v.x)[j]);
    float yn = e * a + bb;
    acc += yn > 0.f ? yn : expm1f(yn);
  }
  for (int m = 32; m; m >>= 1) acc += __shfl_down(acc, m, 64);
  if (lane == 0) out[bo] = acc * (1.f / 256.f);
}

extern "C" void kernel_launch(void* const* d_in, const int* in_sizes, int n_in,
                              void* d_out, int out_size, void* d_ws, size_t ws_size,
                              hipStream_t stream) {
  const float* s1     = (const float*)d_in[0];
  const float* s2     = (const float*)d_in[1];
  const float* s3     = (const float*)d_in[2];
  const float* alpha  = (const float*)d_in[3];
  const float* weight = (const float*)d_in[4];
  const float* bias   = (const float*)d_in[5];
  const float* gamma  = (const float*)d_in[6];
  const float* beta   = (const float*)d_in[7];
  float* out = (float*)d_out;

  char* ws = (char*)d_ws;
  unsigned short* fusedb = (unsigned short*)ws;              // 14,680,064
  unsigned short* qbf    = (unsigned short*)(ws + 14680064); //    114,688
  float* scales          = (float*)(ws + 14794752);          //        512
  unsigned short* ybf    = (unsigned short*)(ws + 14795264); //  4,194,304
  float* Psum            = (float*)(ws + 18989568);          //    262,144
  float* Pssq            = (float*)(ws + 19251712);          //    262,144

  pool_quant_kernel<<<3456, 256, 0, stream>>>(s1, s2, s3, alpha, weight,
                                              fusedb, qbf, scales);
  dim3 g(4, 2, 64);
  mfma_gemm_kernel<<<g, 256, 0, stream>>>(qbf, scales, fusedb, bias, ybf,
                                          Psum, Pssq);
  final_kernel<<<2048, 256, 0, stream>>>(ybf, Psum, Pssq, gamma, beta, out);
}

// Round 12
// 93.164 us; speedup vs baseline: 1.1805x; 1.1805x over previous
//
#include <hip/hip_runtime.h>
#include <hip/hip_bf16.h>

#define EPSV 1e-5f

typedef __attribute__((ext_vector_type(8))) short short8v;
typedef __attribute__((ext_vector_type(4))) short short4v;
typedef __attribute__((ext_vector_type(4))) float float4v;

__device__ inline unsigned short f2bf(float x) {
  __hip_bfloat16 h = __float2bfloat16(x);   // RNE
  return *reinterpret_cast<unsigned short*>(&h);
}
__device__ inline float bf2f(unsigned short b) {
  unsigned u = ((unsigned)b) << 16;
  float f;
  __builtin_memcpy(&f, &u, 4);
  return f;
}

// ---- wave-private pool: one wave, one contiguous span of SPAN floats, ------
// ---- NOUT outputs, no barriers (segment is wave-private). ------------------
// Vectorized variant: span base 16B-aligned, SPAN%4==0.
template <int L, int SPAN, int NOUT, int MAXW>
__device__ __forceinline__ void pool_span_vec(
    const float* __restrict__ spanp, int lbase, float wst,
    unsigned short* __restrict__ outp,   // out base for this span's outputs
    float* __restrict__ seg, int lane) {
  constexpr int S4 = SPAN / 4;
  constexpr int NLD = (S4 + 63) / 64;
  constexpr int OPL = NOUT / 64;        // outputs per lane (2 or 4)
  if (lane < MAXW + 3) seg[SPAN + lane] = 0.f;
  const float4v* rp = (const float4v*)spanp;
  #pragma unroll
  for (int j = 0; j < NLD; ++j) {
    int idx = lane + 64 * j;
    if (NLD * 64 == S4 || idx < S4) {
      float4v v = __builtin_nontemporal_load(rp + idx);
      *(float4v*)&seg[idx * 4] = v;
    }
  }
  constexpr int BASE_SHIFT = (L / SPAN == 2) ? 1 : 0;  // span offset = lbase*L/256
  unsigned short res[OPL];
  #pragma unroll
  for (int oo = 0; oo < OPL; ++oo) {
    int l = lbase + lane * OPL + oo;           // global output index
    int start = ((l * L) >> 8) - ((lbase * L) >> 8 >> BASE_SHIFT << BASE_SHIFT);
    // lbase*L/256 is exact (span boundary): subtract span element offset
    int sbase = (lbase * L) >> 8;
    start = ((l * L) >> 8) - sbase;
    int end = (((l + 1) * L + 255) >> 8) - sbase;
    int width = end - start;
    float s = 0.f;
    #pragma unroll
    for (int i = 0; i < MAXW; ++i) {
      float v = seg[start + i];
      s += (i < width) ? v : 0.f;
    }
    res[oo] = f2bf(s / (float)width * wst);
  }
  if (OPL == 2) {
    unsigned pk = ((unsigned)res[1] << 16) | res[0];
    *(unsigned*)(outp + lane * 2) = pk;
  } else {
    unsigned pk0 = ((unsigned)res[1] << 16) | res[0];
    unsigned pk1 = ((unsigned)res[3] << 16) | res[2];
    unsigned long long pk = ((unsigned long long)pk1 << 32) | pk0;
    *(unsigned long long*)(outp + lane * 4) = pk;
  }
}

// Scalar-load variant (stage3: rows only 4B-aligned).
template <int L, int SPAN, int NOUT, int MAXW>
__device__ __forceinline__ void pool_span_scalar(
    const float* __restrict__ spanp, int lbase, float wst,
    unsigned short* __restrict__ outp, float* __restrict__ seg, int lane) {
  constexpr int NLD = (SPAN + 63) / 64;
  constexpr int OPL = NOUT / 64;
  if (lane < MAXW + 3) seg[SPAN + lane] = 0.f;
  #pragma unroll
  for (int j = 0; j < NLD; ++j) {
    int idx = lane + 64 * j;
    if (idx < SPAN) seg[idx] = __builtin_nontemporal_load(spanp + idx);
  }
  int sbase = (lbase * L) >> 8;
  unsigned short res[OPL];
  #pragma unroll
  for (int oo = 0; oo < OPL; ++oo) {
    int l = lbase + lane * OPL + oo;
    int start = ((l * L) >> 8) - sbase;
    int end = (((l + 1) * L + 255) >> 8) - sbase;
    int width = end - start;
    float s = 0.f;
    #pragma unroll
    for (int i = 0; i < MAXW; ++i) {
      float v = seg[start + i];
      s += (i < width) ? v : 0.f;
    }
    res[oo] = f2bf(s / (float)width * wst);
  }
  unsigned pk0 = ((unsigned)res[1] << 16) | res[0];
  unsigned pk1 = ((unsigned)res[3] << 16) | res[2];
  unsigned long long pk = ((unsigned long long)pk1 << 32) | pk0;
  *(unsigned long long*)(outp + lane * 4) = pk;
}

// ------------- Kernel 1: barrier-free wave-private pool + quant tail --------
// 4 waves/block, each wave fully independent in its 2524-float LDS segment.
// s1 half-rows: [0,8192) blocks (4 halves each)
// s2 full rows: [8192,10240)   s3 full rows: [10240,11264)
// quant: [11264,11392)
__global__ __launch_bounds__(256) void pool_quant_kernel(
    const float* __restrict__ s1, const float* __restrict__ s2,
    const float* __restrict__ s3, const float* __restrict__ alpha,
    const float* __restrict__ w, unsigned short* __restrict__ fusedb,
    unsigned short* __restrict__ qbf, float* __restrict__ scales) {
  __shared__ float pool_lds[4][2524];   // 40,384 B -> 4 blocks/CU
  int bid = blockIdx.x;
  int t = threadIdx.x;
  int wv = t >> 6, lane = t & 63;

  if (bid >= 11264) {               // ---- quant tail ----
    int o = bid - 11264;            // 0..127
    const float* wr = w + o * 448;
    float m = 0.f;
    for (int c = t; c < 448; c += 256) m = fmaxf(m, fabsf(wr[c]));
    float* sm = pool_lds[0];        // reuse LDS
    for (int off = 32; off; off >>= 1) m = fmaxf(m, __shfl_down(m, off, 64));
    if ((t & 63) == 0) sm[t >> 6] = m;
    __syncthreads();
    m = fmaxf(fmaxf(sm[0], sm[1]), fmaxf(sm[2], sm[3]));
    float scale = fmaxf(m, 1e-8f);  // qp = 1 for 2-bit symmetric
    for (int c = t; c < 448; c += 256) {
      float q = rintf(wr[c] / scale);      // RNE == jnp.round
      q = fminf(fmaxf(q, -2.f), 1.f);
      qbf[o * 448 + c] = f2bf(q);          // q in {-2,-1,0,1}: exact bf16
    }
    if (t == 0) scales[o] = scale;
    return;
  }

  float a0 = alpha[0], a1 = alpha[1], a2 = alpha[2];
  float mx = fmaxf(a0, fmaxf(a1, a2));
  float e0 = expf(a0 - mx), e1 = expf(a1 - mx), e2 = expf(a2 - mx);
  float esum = e0 + e1 + e2;
  float* seg = pool_lds[wv];

  if (bid < 8192) {
    // ---- stage1: L=5000; unit = half-row (2500 floats, 128 outputs) ----
    int u = bid * 4 + wv;           // half-row id, 0..32767
    int rr = u >> 1, h = u & 1;     // row 0..16383, half 0/1
    int b = rr >> 8, c = rr & 255;
    const float* spanp = s1 + ((size_t)b * 256 + c) * 5000 + h * 2500;
    unsigned short* outp = fusedb + ((size_t)b * 448 + c) * 256 + h * 128;
    pool_span_vec<5000, 2500, 128, 21>(spanp, h * 128, e0 / esum, outp, seg, lane);
  } else if (bid < 10240) {
    // ---- stage2: L=2500; unit = full row (2500 floats, 256 outputs) ----
    int u = (bid - 8192) * 4 + wv;  // row id, 0..8191
    int b = u >> 7, c = u & 127;
    const float* spanp = s2 + ((size_t)b * 128 + c) * 2500;
    unsigned short* outp = fusedb + ((size_t)b * 448 + 256 + c) * 256;
    pool_span_vec<2500, 2500, 256, 11>(spanp, 0, e1 / esum, outp, seg, lane);
  } else {
    // ---- stage3: L=625; unit = full row (625 floats, 256 outputs) ----
    int u = (bid - 10240) * 4 + wv; // row id, 0..4095
    int b = u >> 6, c = u & 63;
    const float* spanp = s3 + ((size_t)b * 64 + c) * 625;
    unsigned short* outp = fusedb + ((size_t)b * 448 + 384 + c) * 256;
    pool_span_scalar<625, 625, 256, 4>(spanp, 0, e2 / esum, outp, seg, lane);
  }
}

// ------------- Kernel 2: MFMA GEMM -> bf16 y + BN partials ------------------
__global__ __launch_bounds__(256) void mfma_gemm_kernel(
    const unsigned short* __restrict__ qbf, const float* __restrict__ scales,
    const unsigned short* __restrict__ fusedb, const float* __restrict__ bias,
    unsigned short* __restrict__ ybf, float* __restrict__ Psum,
    float* __restrict__ Pssq) {
  __shared__ __align__(16) unsigned short Asm[64][40];
  __shared__ __align__(16) unsigned Bsm32[16][66];   // [k-pair 0..15][n 0..63]
  int b = blockIdx.z;
  int o0 = blockIdx.y * 64;
  int l0 = blockIdx.x * 64;
  int tid = threadIdx.x;
  int wave = tid >> 6, lane = tid & 63;
  int wm = wave >> 1, wn = wave & 1;
  int lrow = lane & 15, lg = lane >> 4;
  const unsigned short* Fp = fusedb + (size_t)b * 448 * 256;
  float4v acc[2][2];
  #pragma unroll
  for (int i = 0; i < 2; ++i)
    #pragma unroll
    for (int j = 0; j < 2; ++j) acc[i][j] = (float4v){0.f, 0.f, 0.f, 0.f};
  for (int c0 = 0; c0 < 448; c0 += 32) {
    { int r = tid >> 2, k0 = (tid & 3) * 8;
      *(short8v*)&Asm[r][k0] = *(const short8v*)(qbf + (size_t)(o0 + r) * 448 + c0 + k0); }
    { int kp = tid >> 4, n0 = (tid & 15) * 4;
      const unsigned short* g0 = Fp + (size_t)(c0 + 2 * kp) * 256 + l0 + n0;
      short4v v0 = *(const short4v*)g0;
      short4v v1 = *(const short4v*)(g0 + 256);
      #pragma unroll
      for (int j = 0; j < 4; ++j)
        Bsm32[kp][n0 + j] =
            (((unsigned)(unsigned short)v1[j]) << 16) | (unsigned short)v0[j];
    }
    __syncthreads();
    short8v af[2];
    #pragma unroll
    for (int mf = 0; mf < 2; ++mf)
      af[mf] = *(const short8v*)&Asm[wm * 32 + mf * 16 + lrow][lg * 8];
    #pragma unroll
    for (int nf = 0; nf < 2; ++nf) {
      int n = wn * 32 + nf * 16 + lrow;
      int tmp[4];
      #pragma unroll
      for (int jj = 0; jj < 4; ++jj) tmp[jj] = (int)Bsm32[lg * 4 + jj][n];
      short8v bf;
      __builtin_memcpy(&bf, tmp, 16);
      #pragma unroll
      for (int mf = 0; mf < 2; ++mf)
        acc[mf][nf] = __builtin_amdgcn_mfma_f32_16x16x32_bf16(af[mf], bf, acc[mf][nf], 0, 0, 0);
    }
    __syncthreads();
  }
  float sv[2][4], qv[2][4];
  #pragma unroll
  for (int mf = 0; mf < 2; ++mf) {
    #pragma unroll
    for (int reg = 0; reg < 4; ++reg) {
      int r = o0 + wm * 32 + mf * 16 + lg * 4 + reg;
      float sc = scales[r], bv = bias[r];
      float s = 0.f, q = 0.f;
      #pragma unroll
      for (int nf = 0; nf < 2; ++nf) {
        int col = l0 + wn * 32 + nf * 16 + lrow;
        float val = acc[mf][nf][reg] * sc + bv;
        ybf[((size_t)b * 128 + r) * 256 + col] = f2bf(val);
        s += val; q += val * val;              // partials from f32 (pre-round)
      }
      sv[mf][reg] = s; qv[mf][reg] = q;
    }
  }
  #pragma unroll
  for (int mf = 0; mf < 2; ++mf)
    #pragma unroll
    for (int reg = 0; reg < 4; ++reg)
      #pragma unroll
      for (int m = 1; m < 16; m <<= 1) {
        sv[mf][reg] += __shfl_xor(sv[mf][reg], m, 64);
        qv[mf][reg] += __shfl_xor(qv[mf][reg], m, 64);
      }
  if (lrow == 0) {
    int slot = b * 8 + blockIdx.x * 2 + wn;   // 0..511 fixed slot
    #pragma unroll
    for (int mf = 0; mf < 2; ++mf)
      #pragma unroll
      for (int reg = 0; reg < 4; ++reg) {
        int r = o0 + wm * 32 + mf * 16 + lg * 4 + reg;
        Psum[r * 512 + slot] = sv[mf][reg];
        Pssq[r * 512 + slot] = qv[mf][reg];
      }
  }
}

// ------------- Kernel 3: inline stats + BN + ELU + mean over L --------------
__global__ __launch_bounds__(256) void final_kernel(
    const unsigned short* __restrict__ ybf, const float* __restrict__ Psum,
    const float* __restrict__ Pssq, const float* __restrict__ gamma,
    const float* __restrict__ beta, float* __restrict__ out) {
  int w = threadIdx.x >> 6;
  int lane = threadIdx.x & 63;
  int bo = blockIdx.x * 4 + w;     // b*128 + o
  int o = bo & 127;

  float s = 0.f, q = 0.f;
  const float* Pp = Psum + o * 512 + lane * 8;
  const float* Qp = Pssq + o * 512 + lane * 8;
  #pragma unroll
  for (int i = 0; i < 8; ++i) { s += Pp[i]; q += Qp[i]; }
  #pragma unroll
  for (int m = 1; m < 64; m <<= 1) {
    s += __shfl_xor(s, m, 64);
    q += __shfl_xor(q, m, 64);
  }
  float mean = s * (1.f / 16384.f);
  float var = q * (1.f / 16384.f) - mean * mean;
  float rs = rsqrtf(var + EPSV);
  float a = rs * gamma[o];
  float bb = beta[o] - mean * a;

  ushort4 v = *(const ushort4*)(ybf + (size_t)bo * 256 + lane * 4);
  float acc = 0.f;
  #pragma unroll
  for (int j = 0; j < 4; ++j) {
    float e = bf2f((&v.x)[j]);
    float yn = e * a + bb;
    acc += yn > 0.f ? yn : expm1f(yn);
  }
  for (int m = 32; m; m >>= 1) acc += __shfl_down(acc, m, 64);
  if (lane == 0) out[bo] = acc * (1.f / 256.f);
}

extern "C" void kernel_launch(void* const* d_in, const int* in_sizes, int n_in,
                              void* d_out, int out_size, void* d_ws, size_t ws_size,
                              hipStream_t stream) {
  const float* s1     = (const float*)d_in[0];
  const float* s2     = (const float*)d_in[1];
  const float* s3     = (const float*)d_in[2];
  const float* alpha  = (const float*)d_in[3];
  const float* weight = (const float*)d_in[4];
  const float* bias   = (const float*)d_in[5];
  const float* gamma  = (const float*)d_in[6];
  const float* beta   = (const float*)d_in[7];
  float* out = (float*)d_out;

  char* ws = (char*)d_ws;
  unsigned short* fusedb = (unsigned short*)ws;              // 14,680,064
  unsigned short* qbf    = (unsigned short*)(ws + 14680064); //    114,688
  float* scales          = (float*)(ws + 14794752);          //        512
  unsigned short* ybf    = (unsigned short*)(ws + 14795264); //  4,194,304
  float* Psum            = (float*)(ws + 18989568);          //    262,144
  float* Pssq            = (float*)(ws + 19251712);          //    262,144

  pool_quant_kernel<<<11392, 256, 0, stream>>>(s1, s2, s3, alpha, weight,
                                               fusedb, qbf, scales);
  dim3 g(4, 2, 64);
  mfma_gemm_kernel<<<g, 256, 0, stream>>>(qbf, scales, fusedb, bias, ybf,
                                          Psum, Pssq);
  final_kernel<<<2048, 256, 0, stream>>>(ybf, Psum, Pssq, gamma, beta, out);
}